// Round 12
// baseline (203.894 us; speedup 1.0000x reference)
//
#include <hip/hip_runtime.h>
#include <hip/hip_bf16.h>

// Problem constants
#define BATCH 2
#define GRP   2
#define NBG   4            // BATCH*GRP
#define CINCH 192          // input channels
#define OG    192          // output channels per group
#define HWDIM 48
#define LPIX  2304         // 48*48
#define KTAP  25           // 5x5
#define IDIM  4800         // CINCH*KTAP
#define NCHUNK 150         // IDIM/32
#define KSPLIT 5           // one kernel row (5 taps) per split
#define XPAD  24576        // 128 l-rows * 192 c of padding each side of g_xt
#define OUTEL (NBG * OG * LPIX)   // 1769472
#define LROW  400          // LDS bytes per staged row (384 data + 16 pad)
#define ZOFF  (132 * LROW) // zero line offset (52800)
#define AOFF  (ZOFF + 64)  // A double-buffer offset; LDS total = AOFF + 16384
#define NTILE 216          // 18 ltile x 3 otile x 4 bg

typedef __attribute__((ext_vector_type(4))) float  float4v;
typedef __attribute__((ext_vector_type(8))) short  short8;

// Static device scratch
// A, fragment-major: [bg][t][ot(3)][i(4)][m(16)][q(4)][e(8)] bf16
__device__ __align__(16) unsigned short g_wa[(size_t)NBG * NCHUNK * 6144];
__device__ __align__(16) unsigned short g_xt[XPAD + BATCH * LPIX * CINCH + XPAD]; // [b][l][c] bf16, padded
__device__ unsigned long long g_m64[NBG * LPIX];   // 50 mask bits per (bg,l)
__device__ __align__(16) unsigned short g_part[(size_t)KSPLIT * OUTEL];  // bf16 K-split partials
__device__ int g_cnt[NTILE];                       // split-K arrival counters

__device__ __forceinline__ unsigned short f2bf(float f) {
  union { float f; unsigned int u; } un; un.f = f;
  unsigned int u = un.u;
  return (unsigned short)((u + 0x7fffu + ((u >> 16) & 1u)) >> 16);  // RNE
}

// ---------------------------------------------------------------------------
// ONE prep dispatch, block ranges:
//  [0,216)      transpose+cvt x -> g_xt
//  [216,984)    reorder dkw -> g_wa (fragment-major, coalesced 64B stores)
//  [984,1176)   mask bits -> g_m64
//  [1176,1200)  zero g_xt pads
//  [1200]       zero split-K counters (EVERY launch — graph-replay safe)
__global__ __launch_bounds__(256) void prep(
    const float* __restrict__ x, const int* __restrict__ tg,
    const float* __restrict__ dkw) {
  __shared__ __align__(16) unsigned char smem[19200];
  const int bx = blockIdx.x, tid = threadIdx.x;

  if (bx < 216) {  // ---- transpose: 64c x 64l tiles via LDS (stride 68)
    unsigned short* tile = (unsigned short*)smem;
    const int c0 = (bx % 3) * 64;
    const int l0 = ((bx / 3) % 36) * 64;
    const int b  = bx / 108;
    #pragma unroll
    for (int it = 0; it < 4; ++it) {
      const int idx = it * 256 + tid;
      const int cl = idx >> 4, lq = idx & 15;
      const float4 v = reinterpret_cast<const float4*>(
          x + ((size_t)b * CINCH + c0 + cl) * LPIX + l0)[lq];
      unsigned short* tp = &tile[cl * 68 + lq * 4];
      tp[0] = f2bf(v.x); tp[1] = f2bf(v.y); tp[2] = f2bf(v.z); tp[3] = f2bf(v.w);
    }
    __syncthreads();
    unsigned short* dst = g_xt + XPAD + ((size_t)b * LPIX) * CINCH;
    #pragma unroll
    for (int it = 0; it < 2; ++it) {
      const int idx = it * 256 + tid;
      const int c8 = idx & 7, ll = idx >> 3;
      unsigned short pk[8];
      #pragma unroll
      for (int e = 0; e < 8; ++e) pk[e] = tile[(c8 * 8 + e) * 68 + ll];
      *reinterpret_cast<uint4*>(dst + (size_t)(l0 + ll) * CINCH + c0 + c8 * 8) =
          *reinterpret_cast<const uint4*>(pk);
    }
  } else if (bx < 984) {  // ---- weight reorder, fragment-major
    float* row = (float*)smem;                 // 4800 floats
    const int blk = bx - 216;                  // bg*192 + o
    const int bg = blk / OG, o = blk % OG;
    const float* src = dkw + (size_t)blk * IDIM;
    for (int i = tid; i < IDIM / 4; i += 256)
      reinterpret_cast<float4*>(row)[i] = reinterpret_cast<const float4*>(src)[i];
    __syncthreads();
    const int ot = o >> 6, fi = (o >> 4) & 3, m = o & 15;
    unsigned short* wbase =
        g_wa + (size_t)bg * NCHUNK * 6144 + ot * 2048 + fi * 512 + m * 32;
    for (int t = tid; t < NCHUNK; t += 256) {  // one 64B granule per t
      const int kk = t / 6, c0 = (t % 6) * 32;
      unsigned int pk[16];
      #pragma unroll
      for (int q = 0; q < 4; ++q)
        #pragma unroll
        for (int e = 0; e < 4; ++e) {
          const int c = c0 + q * 8 + e * 2;
          const unsigned lo = f2bf(row[c * KTAP + kk]);
          const unsigned hi = f2bf(row[(c + 1) * KTAP + kk]);
          pk[q * 4 + e] = lo | (hi << 16);
        }
      unsigned short* dst = wbase + (size_t)t * 6144;
      #pragma unroll
      for (int q = 0; q < 4; ++q)
        reinterpret_cast<uint4*>(dst)[q] = *reinterpret_cast<const uint4*>(pk + q * 4);
    }
  } else if (bx < 1176) {  // ---- mask bits
    const int blk = bx - 984;                  // bg*48 + h
    const int bg = blk / HWDIM, h = blk % HWDIM;
    const int b = bg >> 1, g = bg & 1;
    int* tgs = (int*)smem;                     // [2][5][48]
    for (int i = tid; i < 480; i += 256) {
      const int g2 = i / 240, r5 = (i / 48) % 5, w = i % 48;
      const int hh = h + r5 - 2;
      tgs[i] = (hh >= 0 && hh < HWDIM)
                   ? tg[((b * GRP + g2) * HWDIM + hh) * HWDIM + w]
                   : 0x7fffffff;
    }
    __syncthreads();
    if (tid < HWDIM) {
      const int w = tid;
      const int center = tgs[g * 240 + 96 + w];
      unsigned long long bits = 0ull;
      #pragma unroll
      for (int g2 = 0; g2 < GRP; ++g2)
        #pragma unroll
        for (int kk = 0; kk < KTAP; ++kk) {
          const int ww = w + kk % 5 - 2;
          if (ww >= 0 && ww < HWDIM && tgs[g2 * 240 + (kk / 5) * 48 + ww] < center)
            bits |= 1ull << (g2 * KTAP + kk);
        }
      g_m64[bg * LPIX + h * HWDIM + w] = bits;
    }
  } else if (bx < 1200) {  // ---- zero g_xt pads (2 x 48 KiB)
    const int idx = (bx - 1176) * 256 + tid;   // 0..6143, 16B each
    uint4 z; z.x = z.y = z.z = z.w = 0u;
    if (idx < 3072)
      reinterpret_cast<uint4*>(g_xt)[idx] = z;
    else
      reinterpret_cast<uint4*>(g_xt + XPAD + (size_t)BATCH * LPIX * CINCH)[idx - 3072] = z;
  } else {  // ---- zero split-K counters
    if (tid < NTILE) g_cnt[tid] = 0;
  }
}

// ---------------------------------------------------------------------------
// GEMM (R11 + fused split-K reduction). A flows through an LDS double-buffer
// (8 KB pairs, one barrier per pair); B window staged once (52.8 KB, rows
// padded to 400 B); masked B frags redirect to a zeroed LDS line. XCD-aware
// flat grid of 1080. Block = 2 waves, tile o64 x l128; wave tile o64 x l64.
// Epilogue: all 5 ks-blocks of a tile store bf16 partials, fence, bump the
// tile counter (device-scope); the LAST arrival sums all 5 slots + bias and
// writes fp32 out directly — no separate reduce dispatch.
__global__ __launch_bounds__(128, 2) void gemm_masked(
    const float* __restrict__ dkb, float* __restrict__ out) {
  __shared__ __align__(16) unsigned char sB[AOFF + 16384];

  const int n = blockIdx.x;                  // 0..1079
  const int m = ((n & 7) * 135) + (n >> 3);  // XCD-contiguous work id
  const int ltile = m % 18;                  // l-tile of 128
  const int s  = m / 18;                     // slice 0..59 = (otile,bg,ks)
  const int otile = s % 3;
  const int zz = s / 3;                      // 0..19
  const int bg = zz & 3;
  const int ks = zz >> 2;                    // kernel row 0..4
  const int b  = bg >> 1;
  const int lbase = ltile * 128, obase = otile * 64;
  const int tid = threadIdx.x, lane = tid & 63, wv = tid >> 6;
  const int q = lane >> 4, m16 = lane & 15;

  // per-thread A staging source: granule tid of this block's chunk slice
  const unsigned short* aslab =
      g_wa + ((size_t)bg * NCHUNK + ks * 30) * 6144 + otile * 2048 + tid * 8;

  uint4 ga[4];   // staged A pair: [cc(2)][p(2)]
  // ---- prologue: issue pair-0 A loads first (independent of LDS)
  #pragma unroll
  for (int cc = 0; cc < 2; ++cc)
    #pragma unroll
    for (int p = 0; p < 2; ++p)
      ga[cc * 2 + p] =
          *reinterpret_cast<const uint4*>(aslab + cc * 6144 + p * 1024);

  // ---- stage window rows [wl0, wl0+131] (contiguous in g_xt) into LDS
  const int wl0 = lbase + (ks - 2) * HWDIM - 2;
  const unsigned short* xwin = g_xt + XPAD + (ptrdiff_t)(b * LPIX + wl0) * CINCH;
  #pragma unroll
  for (int it = 0; it < 25; ++it) {          // 132*24 = 3168 granules of 16 B
    const int i = it * 128 + tid;
    if (it < 24 || i < 3168) {
      const int r = i / 24, g = i % 24;      // src is linear: granule i
      *reinterpret_cast<uint4*>(sB + r * LROW + g * 16) =
          *reinterpret_cast<const uint4*>(xwin + i * 8);
    }
  }
  if (tid < 4) {  // zero line
    uint4 z; z.x = z.y = z.z = z.w = 0u;
    *reinterpret_cast<uint4*>(sB + ZOFF + tid * 16) = z;
  }
  // write A pair 0 into buffer 0
  #pragma unroll
  for (int cc = 0; cc < 2; ++cc)
    #pragma unroll
    for (int p = 0; p < 2; ++p)
      *reinterpret_cast<uint4*>(sB + AOFF + cc * 4096 + tid * 16 + p * 2048) =
          ga[cc * 2 + p];

  // ---- per-fragment masks (pre-shifted by ks*5) and LDS base offsets
  unsigned bls[4], bhs[4], bboff[4];
  #pragma unroll
  for (int j = 0; j < 4; ++j) {
    const int lj = wv * 64 + j * 16 + m16;
    const unsigned long long bits = g_m64[bg * LPIX + lbase + lj];
    bls[j] = ((unsigned)(bits & 0x1ffffffull)) >> (ks * 5);
    bhs[j] = ((unsigned)((bits >> KTAP) & 0x1ffffffull)) >> (ks * 5);
    bboff[j] = lj * LROW + q * 16;
  }
  const unsigned zoff = ZOFF + q * 16;

  short8 Bf[2][4];   // 1-deep B prefetch (2 slots)
  #define LOADB(tt)                                                         \
    {                                                                       \
      const int _s = (tt) & 1;                                              \
      const int _kt = (tt) / 6, _ci = (tt) % 6;                             \
      _Pragma("unroll")                                                     \
      for (int j = 0; j < 4; ++j) {                                         \
        const unsigned bit = (((_ci >= 3) ? bhs[j] : bls[j]) >> _kt) & 1u;  \
        const unsigned off =                                                \
            bit ? (bboff[j] + _kt * LROW + _ci * 64) : zoff;                \
        Bf[_s][j] = *reinterpret_cast<const short8*>(sB + off);             \
      }                                                                     \
    }

  float4v acc[4][4];
  #pragma unroll
  for (int i = 0; i < 4; ++i)
    #pragma unroll
    for (int j = 0; j < 4; ++j) acc[i][j] = (float4v)(0.0f);

  __syncthreads();   // window + A pair 0 visible

  LOADB(0)
  #pragma unroll
  for (int pt = 0; pt < 15; ++pt) {
    // issue global loads for pair pt+1 (consumed by ds_write after compute)
    if (pt < 14) {
      const unsigned short* src = aslab + (size_t)(2 * pt + 2) * 6144;
      #pragma unroll
      for (int cc = 0; cc < 2; ++cc)
        #pragma unroll
        for (int p = 0; p < 2; ++p)
          ga[cc * 2 + p] =
              *reinterpret_cast<const uint4*>(src + cc * 6144 + p * 1024);
    }
    // compute pair pt from A buffer (pt&1)
    #pragma unroll
    for (int cc = 0; cc < 2; ++cc) {
      const int tt = 2 * pt + cc;
      short8 Afr[4];
      #pragma unroll
      for (int i = 0; i < 4; ++i)
        Afr[i] = *reinterpret_cast<const short8*>(
            sB + AOFF + (pt & 1) * 8192 + cc * 4096 + i * 1024 + m16 * 64 + q * 16);
      if (tt + 1 < 30) LOADB(tt + 1)
      const int sb = tt & 1;
      #pragma unroll
      for (int i = 0; i < 4; ++i)
        #pragma unroll
        for (int j = 0; j < 4; ++j)
          acc[i][j] = __builtin_amdgcn_mfma_f32_16x16x32_bf16(Afr[i], Bf[sb][j],
                                                              acc[i][j], 0, 0, 0);
    }
    // write pair pt+1 into the other buffer, then ONE barrier
    if (pt < 14) {
      unsigned char* dst = sB + AOFF + ((pt + 1) & 1) * 8192;
      #pragma unroll
      for (int cc = 0; cc < 2; ++cc)
        #pragma unroll
        for (int p = 0; p < 2; ++p)
          *reinterpret_cast<uint4*>(dst + cc * 4096 + tid * 16 + p * 2048) =
              ga[cc * 2 + p];
      __syncthreads();
    }
  }
  #undef LOADB

  // ---- Epilogue 1: bf16 partial stores to g_part[ks][bg][o][l].
  // C/D layout: col = lane&15, row = q*4 + r.
  unsigned short* pb = g_part + (size_t)ks * OUTEL + (size_t)bg * OG * LPIX;
  #pragma unroll
  for (int i = 0; i < 4; ++i) {
    const int og = obase + i * 16 + q * 4;
    #pragma unroll
    for (int j = 0; j < 4; ++j) {
      const int cl = lbase + wv * 64 + j * 16 + m16;
      #pragma unroll
      for (int r = 0; r < 4; ++r)
        pb[(size_t)(og + r) * LPIX + cl] = f2bf(acc[i][j][r]);
    }
  }

  // ---- Epilogue 2: last-arrival reduction (device-scope fence + atomic)
  __threadfence();                           // release partial stores
  __shared__ int lastFlag;
  if (tid == 0) {
    const int t = ltile + 18 * (otile + 3 * bg);
    lastFlag = (atomicAdd(&g_cnt[t], 1) == KSPLIT - 1);
  }
  __syncthreads();
  if (!lastFlag) return;
  __threadfence();                           // acquire others' partials

  const unsigned short* ps =
      g_part + (size_t)bg * OG * LPIX + (size_t)obase * LPIX + lbase;
  const int lc = (tid & 15) * 8;             // 8 l per thread-col
  #pragma unroll
  for (int rr = 0; rr < 8; ++rr) {
    const int r = (tid >> 4) + rr * 8;       // row 0..63
    const float bias = dkb[bg * OG + obase + r];
    float sacc[8];
    #pragma unroll
    for (int k = 0; k < 8; ++k) sacc[k] = bias;
    #pragma unroll
    for (int ksl = 0; ksl < KSPLIT; ++ksl) {
      const uint4 v = *reinterpret_cast<const uint4*>(
          ps + (size_t)ksl * OUTEL + (size_t)r * LPIX + lc);
      const unsigned uu[4] = {v.x, v.y, v.z, v.w};
      #pragma unroll
      for (int p = 0; p < 4; ++p) {
        union { unsigned u; float f; } lo, hi;
        lo.u = uu[p] << 16;
        hi.u = uu[p] & 0xffff0000u;
        sacc[2 * p]     += lo.f;
        sacc[2 * p + 1] += hi.f;
      }
    }
    float4 o0, o1;
    o0.x = sacc[0]; o0.y = sacc[1]; o0.z = sacc[2]; o0.w = sacc[3];
    o1.x = sacc[4]; o1.y = sacc[5]; o1.z = sacc[6]; o1.w = sacc[7];
    float* dst = out + ((size_t)(bg * OG + obase + r)) * LPIX + lbase + lc;
    *reinterpret_cast<float4*>(dst)     = o0;
    *reinterpret_cast<float4*>(dst + 4) = o1;
  }
}

// ---------------------------------------------------------------------------
extern "C" void kernel_launch(void* const* d_in, const int* in_sizes, int n_in,
                              void* d_out, int out_size, void* d_ws, size_t ws_size,
                              hipStream_t stream) {
  const float* x   = (const float*)d_in[0];
  const int*   tg  = (const int*)d_in[1];
  const float* dkw = (const float*)d_in[2];
  const float* dkb = (const float*)d_in[3];
  float* out = (float*)d_out;

  prep<<<dim3(1201), 256, 0, stream>>>(x, tg, dkw);
  gemm_masked<<<dim3(1080), 128, 0, stream>>>(dkb, out);
}

// Round 13
// 124.063 us; speedup vs baseline: 1.6435x; 1.6435x over previous
//
#include <hip/hip_runtime.h>
#include <hip/hip_bf16.h>

// Problem constants
#define BATCH 2
#define GRP   2
#define NBG   4            // BATCH*GRP
#define CINCH 192          // input channels
#define OG    192          // output channels per group
#define HWDIM 48
#define LPIX  2304         // 48*48
#define KTAP  25           // 5x5
#define IDIM  4800         // CINCH*KTAP
#define NCHUNK 150         // IDIM/32
#define KSPLIT 5           // one kernel row (5 taps) per split
#define XPAD  24576        // 128 l-rows * 192 c of padding each side of g_xt
#define OUTEL (NBG * OG * LPIX)   // 1769472
#define BROW  208          // LDS bytes per staged HALF row (192 data + 16 pad)
#define ZBASE (132 * BROW) // zero region offset (27456), 1024 B
#define ABUF  (ZBASE + 1024) // A double-buffer offset (28480); total 53056 B

typedef __attribute__((ext_vector_type(4))) float  float4v;
typedef __attribute__((ext_vector_type(8))) short  short8;

// Static device scratch
// A, fragment-major: [bg][t][ot(3)][i(4)][m(16)][q(4)][e(8)] bf16
__device__ __align__(16) unsigned short g_wa[(size_t)NBG * NCHUNK * 6144];
__device__ __align__(16) unsigned short g_xt[XPAD + BATCH * LPIX * CINCH + XPAD]; // [b][l][c] bf16, padded
__device__ unsigned long long g_m64[NBG * LPIX];   // 50 mask bits per (bg,l)
__device__ __align__(16) unsigned short g_part[(size_t)KSPLIT * OUTEL];  // bf16 K-split partials

__device__ __forceinline__ unsigned short f2bf(float f) {
  union { float f; unsigned int u; } un; un.f = f;
  unsigned int u = un.u;
  return (unsigned short)((u + 0x7fffu + ((u >> 16) & 1u)) >> 16);  // RNE
}

// ---------------------------------------------------------------------------
// ONE prep dispatch, block ranges:
//  [0,216)      transpose+cvt x -> g_xt
//  [216,984)    reorder dkw -> g_wa (fragment-major, coalesced 64B stores)
//  [984,1176)   mask bits -> g_m64
//  [1176,1200)  zero g_xt pads
__global__ __launch_bounds__(256) void prep(
    const float* __restrict__ x, const int* __restrict__ tg,
    const float* __restrict__ dkw) {
  __shared__ __align__(16) unsigned char smem[19200];
  const int bx = blockIdx.x, tid = threadIdx.x;

  if (bx < 216) {  // ---- transpose: 64c x 64l tiles via LDS (stride 68)
    unsigned short* tile = (unsigned short*)smem;
    const int c0 = (bx % 3) * 64;
    const int l0 = ((bx / 3) % 36) * 64;
    const int b  = bx / 108;
    #pragma unroll
    for (int it = 0; it < 4; ++it) {
      const int idx = it * 256 + tid;
      const int cl = idx >> 4, lq = idx & 15;
      const float4 v = reinterpret_cast<const float4*>(
          x + ((size_t)b * CINCH + c0 + cl) * LPIX + l0)[lq];
      unsigned short* tp = &tile[cl * 68 + lq * 4];
      tp[0] = f2bf(v.x); tp[1] = f2bf(v.y); tp[2] = f2bf(v.z); tp[3] = f2bf(v.w);
    }
    __syncthreads();
    unsigned short* dst = g_xt + XPAD + ((size_t)b * LPIX) * CINCH;
    #pragma unroll
    for (int it = 0; it < 2; ++it) {
      const int idx = it * 256 + tid;
      const int c8 = idx & 7, ll = idx >> 3;
      unsigned short pk[8];
      #pragma unroll
      for (int e = 0; e < 8; ++e) pk[e] = tile[(c8 * 8 + e) * 68 + ll];
      *reinterpret_cast<uint4*>(dst + (size_t)(l0 + ll) * CINCH + c0 + c8 * 8) =
          *reinterpret_cast<const uint4*>(pk);
    }
  } else if (bx < 984) {  // ---- weight reorder, fragment-major
    float* row = (float*)smem;                 // 4800 floats
    const int blk = bx - 216;                  // bg*192 + o
    const int bg = blk / OG, o = blk % OG;
    const float* src = dkw + (size_t)blk * IDIM;
    for (int i = tid; i < IDIM / 4; i += 256)
      reinterpret_cast<float4*>(row)[i] = reinterpret_cast<const float4*>(src)[i];
    __syncthreads();
    const int ot = o >> 6, fi = (o >> 4) & 3, m = o & 15;
    unsigned short* wbase =
        g_wa + (size_t)bg * NCHUNK * 6144 + ot * 2048 + fi * 512 + m * 32;
    for (int t = tid; t < NCHUNK; t += 256) {  // one 64B granule per t
      const int kk = t / 6, c0 = (t % 6) * 32;
      unsigned int pk[16];
      #pragma unroll
      for (int q = 0; q < 4; ++q)
        #pragma unroll
        for (int e = 0; e < 4; ++e) {
          const int c = c0 + q * 8 + e * 2;
          const unsigned lo = f2bf(row[c * KTAP + kk]);
          const unsigned hi = f2bf(row[(c + 1) * KTAP + kk]);
          pk[q * 4 + e] = lo | (hi << 16);
        }
      unsigned short* dst = wbase + (size_t)t * 6144;
      #pragma unroll
      for (int q = 0; q < 4; ++q)
        reinterpret_cast<uint4*>(dst)[q] = *reinterpret_cast<const uint4*>(pk + q * 4);
    }
  } else if (bx < 1176) {  // ---- mask bits
    const int blk = bx - 984;                  // bg*48 + h
    const int bg = blk / HWDIM, h = blk % HWDIM;
    const int b = bg >> 1, g = bg & 1;
    int* tgs = (int*)smem;                     // [2][5][48]
    for (int i = tid; i < 480; i += 256) {
      const int g2 = i / 240, r5 = (i / 48) % 5, w = i % 48;
      const int hh = h + r5 - 2;
      tgs[i] = (hh >= 0 && hh < HWDIM)
                   ? tg[((b * GRP + g2) * HWDIM + hh) * HWDIM + w]
                   : 0x7fffffff;
    }
    __syncthreads();
    if (tid < HWDIM) {
      const int w = tid;
      const int center = tgs[g * 240 + 96 + w];
      unsigned long long bits = 0ull;
      #pragma unroll
      for (int g2 = 0; g2 < GRP; ++g2)
        #pragma unroll
        for (int kk = 0; kk < KTAP; ++kk) {
          const int ww = w + kk % 5 - 2;
          if (ww >= 0 && ww < HWDIM && tgs[g2 * 240 + (kk / 5) * 48 + ww] < center)
            bits |= 1ull << (g2 * KTAP + kk);
        }
      g_m64[bg * LPIX + h * HWDIM + w] = bits;
    }
  } else {  // ---- zero g_xt pads (2 x 48 KiB)
    const int idx = (bx - 1176) * 256 + tid;   // 0..6143, 16B each
    uint4 z; z.x = z.y = z.z = z.w = 0u;
    if (idx < 3072)
      reinterpret_cast<uint4*>(g_xt)[idx] = z;
    else
      reinterpret_cast<uint4*>(g_xt + XPAD + (size_t)BATCH * LPIX * CINCH)[idx - 3072] = z;
  }
}

// ---------------------------------------------------------------------------
// GEMM (R13 = R11 + half-B windows + zero-REGION). B window staged one
// c-half at a time (132 rows x 208 B = 27.5 KB; chunks regrouped by g2-half,
// one mid-kernel restage). Masked B lanes read a 1 KB zero region at
// ZBASE + m16*64 + q*16 (uniform bank groups — no conflict pileup).
// A flows through a 12 KB-pair LDS double-buffer (3 chunks/stage, one
// barrier per stage). LDS total 53 KB -> 3 blocks/CU (6 waves/CU).
// XCD-aware flat grid of 1080. Block = 2 waves, tile o64 x l128; wave tile
// o64 x l64 (4x4 16x16x32 MFMA). K-split over kernel rows; bf16 partials.
__global__ __launch_bounds__(128, 2) void gemm_masked() {
  __shared__ __align__(16) unsigned char sB[ABUF + 24576];

  const int n = blockIdx.x;                  // 0..1079
  const int m = ((n & 7) * 135) + (n >> 3);  // XCD-contiguous work id
  const int ltile = m % 18;                  // l-tile of 128
  const int s  = m / 18;                     // slice 0..59 = (otile,bg,ks)
  const int otile = s % 3;
  const int zz = s / 3;                      // 0..19
  const int bg = zz & 3;
  const int ks = zz >> 2;                    // kernel row 0..4
  const int b  = bg >> 1;
  const int lbase = ltile * 128, obase = otile * 64;
  const int tid = threadIdx.x, lane = tid & 63, wv = tid >> 6;
  const int q = lane >> 4, m16 = lane & 15;

  // per-thread A staging source: granule tid of this block's chunk slice
  const unsigned short* aslab =
      g_wa + ((size_t)bg * NCHUNK + ks * 30) * 6144 + otile * 2048 + tid * 8;

  // chunk t (rel) for stage gs, sub cc: h=gs/5, kt=gs%5 -> t = kt*6 + h*3 + cc
  uint4 ga[6];   // staged A stage: [cc(3)][p(2)]
  #define GLOADA(gs)                                                        \
    {                                                                       \
      const int _t0 = ((gs) % 5) * 6 + ((gs) / 5) * 3;                      \
      _Pragma("unroll")                                                     \
      for (int cc = 0; cc < 3; ++cc)                                        \
        _Pragma("unroll")                                                   \
        for (int p = 0; p < 2; ++p)                                         \
          ga[cc * 2 + p] = *reinterpret_cast<const uint4*>(                 \
              aslab + (size_t)(_t0 + cc) * 6144 + p * 1024);                \
    }
  #define SWRITEA(buf)                                                     \
    {                                                                       \
      unsigned char* _d = sB + ABUF + (buf) * 12288;                        \
      _Pragma("unroll")                                                     \
      for (int cc = 0; cc < 3; ++cc)                                        \
        _Pragma("unroll")                                                   \
        for (int p = 0; p < 2; ++p)                                         \
          *reinterpret_cast<uint4*>(_d + cc * 4096 + tid * 16 + p * 2048) = \
              ga[cc * 2 + p];                                               \
    }

  // ---- prologue: issue stage-0 A loads first (independent of LDS)
  GLOADA(0)

  // ---- stage B half0: window rows [wl0, wl0+131], c in [0,96)
  const int wl0 = lbase + (ks - 2) * HWDIM - 2;
  const unsigned short* xwin = g_xt + XPAD + (ptrdiff_t)(b * LPIX + wl0) * CINCH;
  #pragma unroll
  for (int it = 0; it < 13; ++it) {          // 132*12 = 1584 granules of 16 B
    const int i = it * 128 + tid;
    if (it < 12 || i < 1584) {
      const int r = i / 12, g = i % 12;
      *reinterpret_cast<uint4*>(sB + r * BROW + g * 16) =
          *reinterpret_cast<const uint4*>(xwin + r * CINCH + g * 8);
    }
  }
  if (tid < 64) {  // zero region (1 KB)
    uint4 z; z.x = z.y = z.z = z.w = 0u;
    *reinterpret_cast<uint4*>(sB + ZBASE + tid * 16) = z;
  }
  SWRITEA(0)

  // ---- per-fragment masks (pre-shifted by ks*5) and LDS base offsets
  unsigned bls[4], bhs[4], bboff[4];
  #pragma unroll
  for (int j = 0; j < 4; ++j) {
    const int lj = wv * 64 + j * 16 + m16;
    const unsigned long long bits = g_m64[bg * LPIX + lbase + lj];
    bls[j] = ((unsigned)(bits & 0x1ffffffull)) >> (ks * 5);
    bhs[j] = ((unsigned)((bits >> KTAP) & 0x1ffffffull)) >> (ks * 5);
    bboff[j] = lj * BROW + q * 16;
  }
  const unsigned zoff = ZBASE + m16 * 64 + q * 16;

  short8 Bf[2][4];   // 1-deep B prefetch (2 slots)
  #define LOADB(u)                                                          \
    {                                                                       \
      const int _s = (u) & 1;                                               \
      const int _h = (u) / 15, _kt = ((u) % 15) / 3, _c3 = (u) % 3;         \
      _Pragma("unroll")                                                     \
      for (int j = 0; j < 4; ++j) {                                         \
        const unsigned bit = ((_h ? bhs[j] : bls[j]) >> _kt) & 1u;          \
        const unsigned off =                                                \
            bit ? (bboff[j] + _kt * BROW + _c3 * 64) : zoff;                \
        Bf[_s][j] = *reinterpret_cast<const short8*>(sB + off);             \
      }                                                                     \
    }

  float4v acc[4][4];
  #pragma unroll
  for (int i = 0; i < 4; ++i)
    #pragma unroll
    for (int j = 0; j < 4; ++j) acc[i][j] = (float4v)(0.0f);

  __syncthreads();   // half0 + A stage 0 visible

  LOADB(0)
  #pragma unroll
  for (int gs = 0; gs < 10; ++gs) {
    // issue global loads for stage gs+1
    if (gs < 9) GLOADA(gs + 1)
    // compute 3 chunks of stage gs from A buffer (gs&1)
    #pragma unroll
    for (int cc = 0; cc < 3; ++cc) {
      const int u = gs * 3 + cc;
      short8 Afr[4];
      #pragma unroll
      for (int i = 0; i < 4; ++i)
        Afr[i] = *reinterpret_cast<const short8*>(
            sB + ABUF + (gs & 1) * 12288 + cc * 4096 + i * 1024 + m16 * 64 + q * 16);
      if (u + 1 < 30 && u + 1 != 15) LOADB(u + 1)
      const int sb = u & 1;
      #pragma unroll
      for (int i = 0; i < 4; ++i)
        #pragma unroll
        for (int j = 0; j < 4; ++j)
          acc[i][j] = __builtin_amdgcn_mfma_f32_16x16x32_bf16(Afr[i], Bf[sb][j],
                                                              acc[i][j], 0, 0, 0);
    }
    if (gs == 4) {
      __syncthreads();   // all waves done reading half0
      // restage B half1 (c in [96,192))
      #pragma unroll
      for (int it = 0; it < 13; ++it) {
        const int i = it * 128 + tid;
        if (it < 12 || i < 1584) {
          const int r = i / 12, g = i % 12;
          *reinterpret_cast<uint4*>(sB + r * BROW + g * 16) =
              *reinterpret_cast<const uint4*>(xwin + r * CINCH + 96 + g * 8);
        }
      }
      SWRITEA(1)         // A stage 5 -> buf 1
      __syncthreads();
      LOADB(15)          // restart B prefetch chain
    } else if (gs < 9) {
      SWRITEA((gs + 1) & 1)
      __syncthreads();
    }
  }
  #undef LOADB
  #undef GLOADA
  #undef SWRITEA

  // Epilogue: bf16 partial stores to g_part[ks][bg][o][l].
  // C/D layout: col = lane&15, row = q*4 + r.
  unsigned short* pb = g_part + (size_t)ks * OUTEL + (size_t)bg * OG * LPIX;
  #pragma unroll
  for (int i = 0; i < 4; ++i) {
    const int og = obase + i * 16 + q * 4;
    #pragma unroll
    for (int j = 0; j < 4; ++j) {
      const int cl = lbase + wv * 64 + j * 16 + m16;
      #pragma unroll
      for (int r = 0; r < 4; ++r)
        pb[(size_t)(og + r) * LPIX + cl] = f2bf(acc[i][j][r]);
    }
  }
}

// ---------------------------------------------------------------------------
// Reduce: out = sum_ks bf16(g_part[ks]) + bias. 8 elements per thread.
__global__ __launch_bounds__(256) void reduce_part(
    const float* __restrict__ dkb, float* __restrict__ out) {
  const int t8 = blockIdx.x * 256 + threadIdx.x;   // 0..221183
  const size_t e0 = (size_t)t8 * 8;
  const int row = (int)(e0 / LPIX);                // bg*192 + o (8 els same row)
  const float bias = dkb[row];
  float s[8];
  #pragma unroll
  for (int k = 0; k < 8; ++k) s[k] = bias;
  #pragma unroll
  for (int ks = 0; ks < KSPLIT; ++ks) {
    const uint4 v = *reinterpret_cast<const uint4*>(
        g_part + (size_t)ks * OUTEL + e0);
    const unsigned u[4] = {v.x, v.y, v.z, v.w};
    #pragma unroll
    for (int p = 0; p < 4; ++p) {
      union { unsigned u; float f; } lo, hi;
      lo.u = u[p] << 16;
      hi.u = u[p] & 0xffff0000u;
      s[2 * p]     += lo.f;
      s[2 * p + 1] += hi.f;
    }
  }
  float4 o0, o1;
  o0.x = s[0]; o0.y = s[1]; o0.z = s[2]; o0.w = s[3];
  o1.x = s[4]; o1.y = s[5]; o1.z = s[6]; o1.w = s[7];
  reinterpret_cast<float4*>(out)[t8 * 2]     = o0;
  reinterpret_cast<float4*>(out)[t8 * 2 + 1] = o1;
}

// ---------------------------------------------------------------------------
extern "C" void kernel_launch(void* const* d_in, const int* in_sizes, int n_in,
                              void* d_out, int out_size, void* d_ws, size_t ws_size,
                              hipStream_t stream) {
  const float* x   = (const float*)d_in[0];
  const int*   tg  = (const int*)d_in[1];
  const float* dkw = (const float*)d_in[2];
  const float* dkb = (const float*)d_in[3];
  float* out = (float*)d_out;

  prep<<<dim3(1200), 256, 0, stream>>>(x, tg, dkw);
  gemm_masked<<<dim3(1080), 128, 0, stream>>>();
  reduce_part<<<dim3(OUTEL / 2048), 256, 0, stream>>>(dkb, out);
}